// Round 1
// baseline (1931.195 us; speedup 1.0000x reference)
//
#include <hip/hip_runtime.h>
#include <math.h>

#define N1 8192
#define N2 8192
#define DDIM 256
#define BETA2 40.5f

#define BM 32
#define BK 64
#define TBLOCK 512

// Kernel 1: V[j][k] = cos(p2_j . A_k), V[j][256+k] = sin(p2_j . A_k)
__global__ void feat_kernel(const float* __restrict__ p2,
                            const float* __restrict__ A,
                            float* __restrict__ V) {
    int j = blockIdx.x;
    int k = threadIdx.x;
    float x = p2[j * 3 + 0], y = p2[j * 3 + 1], z = p2[j * 3 + 2];
    float th = fmaf(x, A[k], fmaf(y, A[DDIM + k], z * A[2 * DDIM + k]));
    float s, c;
    sincosf(th, &s, &c);
    V[(size_t)j * (2 * DDIM) + k] = c;
    V[(size_t)j * (2 * DDIM) + DDIM + k] = s;
}

// Main kernel: block owns BM=32 rows of pointset1 and ALL 512 feature columns.
// 8 waves: wave rg owns rows rg*4..rg*4+3; lane cg owns complex cols cg*4..cg*4+3.
// Inner product: acc[m][c] += J[row m][j] * V[j][col c], J tile built in LDS.
__global__ __launch_bounds__(TBLOCK) void main_kernel(
    const float* __restrict__ p1, const float* __restrict__ p2,
    const float* __restrict__ A, const float* __restrict__ P,
    const float* __restrict__ V, float* __restrict__ out) {

    __shared__ float p1s[BM * 3];
    __shared__ float p2s[BK * 3];
    __shared__ float wls[BK][BM];   // J tile, j-major so w-reads are contiguous in m

    const int tid = threadIdx.x;
    const int rg = tid >> 6;        // wave id 0..7
    const int cg = tid & 63;        // lane 0..63
    const int i0 = blockIdx.x * BM;
    const int kb = cg * 4;          // complex column base (0..252)
    const int mrow = rg * 4;        // first local row of this wave

    if (tid < BM * 3) p1s[tid] = p1[(size_t)i0 * 3 + tid];

    float accr[4][4], acci[4][4];
    #pragma unroll
    for (int m = 0; m < 4; ++m)
        #pragma unroll
        for (int c = 0; c < 4; ++c) { accr[m][c] = 0.f; acci[m][c] = 0.f; }

    for (int jc = 0; jc < N2; jc += BK) {
        __syncthreads();            // protect p2s/wls from previous iteration readers
        if (tid < BK * 3) p2s[tid] = p2[(size_t)jc * 3 + tid];
        __syncthreads();
        // build J tile: 2048 weights, 4 per thread
        #pragma unroll
        for (int r = 0; r < (BM * BK / TBLOCK); ++r) {
            int idx = tid + r * TBLOCK;
            int m = idx & (BM - 1);
            int j = idx >> 5;
            float dx = p1s[m * 3 + 0] - p2s[j * 3 + 0];
            float dy = p1s[m * 3 + 1] - p2s[j * 3 + 1];
            float dz = p1s[m * 3 + 2] - p2s[j * 3 + 2];
            float d2 = fmaf(dx, dx, fmaf(dy, dy, dz * dz));
            wls[j][m] = __expf(-BETA2 * d2);
        }
        __syncthreads();
        const float* Vp = V + (size_t)jc * (2 * DDIM) + kb;
        #pragma unroll 8
        for (int j = 0; j < BK; ++j) {
            float4 vr = *(const float4*)(Vp);             // cos values, 4 cols
            float4 vi = *(const float4*)(Vp + DDIM);      // sin values, 4 cols
            float4 w  = *(const float4*)(&wls[j][mrow]);  // 4 rows' weights (wave-broadcast)
            float wv[4]  = {w.x, w.y, w.z, w.w};
            float vrv[4] = {vr.x, vr.y, vr.z, vr.w};
            float viv[4] = {vi.x, vi.y, vi.z, vi.w};
            #pragma unroll
            for (int m = 0; m < 4; ++m)
                #pragma unroll
                for (int c = 0; c < 4; ++c) {
                    accr[m][c] = fmaf(wv[m], vrv[c], accr[m][c]);
                    acci[m][c] = fmaf(wv[m], viv[c], acci[m][c]);
                }
            Vp += 2 * DDIM;
        }
    }

    // ---- epilogue ----
    // row norms: |G/eP1| == |G| (unit rotation), so reduce raw accumulators.
    float part[4];
    #pragma unroll
    for (int m = 0; m < 4; ++m) {
        float s = 0.f;
        #pragma unroll
        for (int c = 0; c < 4; ++c)
            s += accr[m][c] * accr[m][c] + acci[m][c] * acci[m][c];
        part[m] = s;
    }
    #pragma unroll
    for (int off = 32; off > 0; off >>= 1) {
        #pragma unroll
        for (int m = 0; m < 4; ++m)
            part[m] += __shfl_xor(part[m], off, 64);
    }
    float scale[4];
    #pragma unroll
    for (int m = 0; m < 4; ++m) scale[m] = 16.0f * rsqrtf(part[m]);

    #pragma unroll
    for (int m = 0; m < 4; ++m) {
        int row = mrow + m;
        float x = p1s[row * 3 + 0], y = p1s[row * 3 + 1], z = p1s[row * 3 + 2];
        float res[8];
        #pragma unroll
        for (int c = 0; c < 4; ++c) {
            int k = kb + c;
            float th1 = fmaf(x, A[k], fmaf(y, A[DDIM + k], z * A[2 * DDIM + k]));
            float thp = fmaf(x, P[k], fmaf(y, P[DDIM + k], z * P[2 * DDIM + k]));
            float s1, c1, sp, cp;
            sincosf(th1, &s1, &c1);
            sincosf(thp, &sp, &cp);
            float gr = accr[m][c], gi = acci[m][c];
            // G * conj(eP1) * scale + PE
            res[2 * c + 0] = fmaf(gr, c1, gi * s1) * scale[m] + cp;
            res[2 * c + 1] = fmaf(gi, c1, -gr * s1) * scale[m] + sp;
        }
        float* op = out + (size_t)(i0 + row) * (2 * DDIM) + (size_t)kb * 2;
        *(float4*)(op + 0) = make_float4(res[0], res[1], res[2], res[3]);
        *(float4*)(op + 4) = make_float4(res[4], res[5], res[6], res[7]);
    }
}

extern "C" void kernel_launch(void* const* d_in, const int* in_sizes, int n_in,
                              void* d_out, int out_size, void* d_ws, size_t ws_size,
                              hipStream_t stream) {
    const float* p1 = (const float*)d_in[0];
    const float* p2 = (const float*)d_in[1];
    const float* A  = (const float*)d_in[2];
    const float* P  = (const float*)d_in[3];
    float* V = (float*)d_ws;                 // 8192 x 512 f32 = 16.8 MB
    float* out = (float*)d_out;

    feat_kernel<<<N2, DDIM, 0, stream>>>(p2, A, V);
    main_kernel<<<N1 / BM, TBLOCK, 0, stream>>>(p1, p2, A, P, V, out);
}

// Round 2
// 256.321 us; speedup vs baseline: 7.5343x; 7.5343x over previous
//
#include <hip/hip_runtime.h>
#include <math.h>

#define N1 8192
#define N2 8192
#define BETA2 40.5f

typedef short bf16x8 __attribute__((ext_vector_type(8)));
typedef float f32x4 __attribute__((ext_vector_type(4)));
typedef unsigned short ushort8 __attribute__((ext_vector_type(8)));

__device__ __forceinline__ unsigned short bf16bits(float f) {
    union { float f; unsigned u; } x; x.f = f;
    unsigned r = x.u + 0x7fff + ((x.u >> 16) & 1);   // RNE
    return (unsigned short)(r >> 16);
}

// Vf layout: [kblock = k/8][n = 0..511][e = k%8] bf16.
// n in 0..255 -> cos(p2_k . A_n); n in 256..511 -> sin(p2_k . A_{n-256}).
// Block handles 8 consecutive k (= one kblock), thread t owns col n=t, writes 16B.
__global__ __launch_bounds__(512) void feat_kernel(const float* __restrict__ p2,
                                                   const float* __restrict__ A,
                                                   unsigned short* __restrict__ Vf) {
    __shared__ float p2s[24];
    const int t = threadIdx.x;
    const int j0 = blockIdx.x * 8;
    if (t < 24) p2s[t] = p2[(size_t)j0 * 3 + t];
    __syncthreads();
    const int k = t & 255, part = t >> 8;
    const float a0 = A[k], a1 = A[256 + k], a2 = A[512 + k];
    ushort8 v8;
    #pragma unroll
    for (int j = 0; j < 8; ++j) {
        float th = fmaf(p2s[j * 3], a0, fmaf(p2s[j * 3 + 1], a1, p2s[j * 3 + 2] * a2));
        float s, c;
        sincosf(th, &s, &c);
        v8[j] = bf16bits(part ? s : c);
    }
    *(ushort8*)(Vf + (size_t)blockIdx.x * 4096 + t * 8) = v8;
}

// GEMM: C[8192][512] = J[8192][8192] @ V[8192][512], J built on the fly (bf16),
// MFMA 16x16x32_bf16. Block = 128 rows x 128 cols (cols = 64 complex cols, both re+im).
// cg = blockIdx.x % 4 so each XCD (bid%8) sees one col-group -> V slice L2-resident.
// Raw G written straight into d_out (interleaved re/im); row-norm partials to ws.
__global__ __launch_bounds__(512) void gemm_kernel(const float* __restrict__ p1,
                                                   const float* __restrict__ p2,
                                                   const unsigned short* __restrict__ Vf,
                                                   float* __restrict__ out,
                                                   float* __restrict__ normpart) {
    __shared__ unsigned int Jlds[4096];   // 128 rows x 64 k bf16, XOR-swizzled
    __shared__ float p1s[384];
    __shared__ float normp[8][64];

    const int t = threadIdx.x;
    const int l = t & 63;
    const int wid = t >> 6;
    const int wm = wid >> 2;      // 0..1  (row half)
    const int wn = wid & 3;       // 0..3  (col quarter: 0,1=cos/re  2,3=sin/im)
    const int g = l >> 4;         // lane k-group
    const int ln = l & 15;
    const int cg = blockIdx.x & 3;
    const int i0 = (blockIdx.x >> 2) * 128;

    if (t < 384) p1s[t] = p1[(size_t)i0 * 3 + t];

    f32x4 acc[4][2] = {};

    // J-build assignment: thread owns k-pair kp (fixed), rows r*16 + tm.
    const int kp = t & 31;
    const int tm = t >> 5;

    // B column base for (wn, nr): nb = side*256 + cg*64 + (wn&1)*32 + nr*16 + ln
    const int nb0 = (wn >> 1) * 256 + cg * 64 + (wn & 1) * 32 + ln;

    // prefetch p2 for first K-step
    float qx0 = p2[(size_t)(kp * 2) * 3 + 0], qy0 = p2[(size_t)(kp * 2) * 3 + 1], qz0 = p2[(size_t)(kp * 2) * 3 + 2];
    float qx1 = p2[(size_t)(kp * 2) * 3 + 3], qy1 = p2[(size_t)(kp * 2) * 3 + 4], qz1 = p2[(size_t)(kp * 2) * 3 + 5];

    for (int jc = 0; jc < N2; jc += 64) {
        __syncthreads();   // previous MFMA phase done reading Jlds (also covers p1s on iter 0)
        #pragma unroll
        for (int r = 0; r < 8; ++r) {
            int m = r * 16 + tm;
            float px = p1s[m * 3], py = p1s[m * 3 + 1], pz = p1s[m * 3 + 2];
            float dx0 = px - qx0, dy0 = py - qy0, dz0 = pz - qz0;
            float dx1 = px - qx1, dy1 = py - qy1, dz1 = pz - qz1;
            float d20 = fmaf(dx0, dx0, fmaf(dy0, dy0, dz0 * dz0));
            float d21 = fmaf(dx1, dx1, fmaf(dy1, dy1, dz1 * dz1));
            unsigned int pk = (unsigned int)bf16bits(__expf(-BETA2 * d20))
                            | ((unsigned int)bf16bits(__expf(-BETA2 * d21)) << 16);
            int byte = (m * 128 + kp * 4) ^ ((m & 7) << 4);
            Jlds[byte >> 2] = pk;
        }
        __syncthreads();
        // prefetch p2 for next K-step (hidden under MFMA phase)
        {
            int kn = (jc + 64 < N2) ? (jc + 64 + kp * 2) : (kp * 2);
            qx0 = p2[(size_t)kn * 3 + 0]; qy0 = p2[(size_t)kn * 3 + 1]; qz0 = p2[(size_t)kn * 3 + 2];
            qx1 = p2[(size_t)kn * 3 + 3]; qy1 = p2[(size_t)kn * 3 + 4]; qz1 = p2[(size_t)kn * 3 + 5];
        }
        #pragma unroll
        for (int kk = 0; kk < 2; ++kk) {
            bf16x8 bfr[2];
            #pragma unroll
            for (int nr = 0; nr < 2; ++nr) {
                size_t idx = (size_t)((jc >> 3) + kk * 4 + g) * 4096 + (size_t)(nb0 + nr * 16) * 8;
                bfr[nr] = *(const bf16x8*)(Vf + idx);
            }
            #pragma unroll
            for (int mr = 0; mr < 4; ++mr) {
                int m = wm * 64 + mr * 16 + ln;
                int byte = (m * 128 + kk * 64 + g * 16) ^ ((m & 7) << 4);
                bf16x8 af = *(const bf16x8*)((const char*)Jlds + byte);
                #pragma unroll
                for (int nr = 0; nr < 2; ++nr)
                    acc[mr][nr] = __builtin_amdgcn_mfma_f32_16x16x32_bf16(af, bfr[nr], acc[mr][nr], 0, 0, 0);
            }
        }
    }

    // ---- row-norm partials (sum of squares over this block's 32 cols per wave) ----
    #pragma unroll
    for (int mr = 0; mr < 4; ++mr) {
        #pragma unroll
        for (int reg = 0; reg < 4; ++reg) {
            float s = acc[mr][0][reg] * acc[mr][0][reg] + acc[mr][1][reg] * acc[mr][1][reg];
            #pragma unroll
            for (int off = 1; off < 16; off <<= 1) s += __shfl_xor(s, off, 64);
            if (ln == 0) normp[wid][mr * 16 + g * 4 + reg] = s;
        }
    }
    __syncthreads();
    if (t < 128) {
        int wmm = t >> 6;
        int r6 = t & 63;
        float s = normp[wmm * 4 + 0][r6] + normp[wmm * 4 + 1][r6]
                + normp[wmm * 4 + 2][r6] + normp[wmm * 4 + 3][r6];
        normpart[(size_t)cg * N1 + i0 + t] = s;
    }

    // ---- store raw G into out (interleaved re/im) ----
    const int comp = wn >> 1;
    #pragma unroll
    for (int mr = 0; mr < 4; ++mr) {
        #pragma unroll
        for (int reg = 0; reg < 4; ++reg) {
            int row = i0 + wm * 64 + mr * 16 + g * 4 + reg;
            #pragma unroll
            for (int nr = 0; nr < 2; ++nr) {
                int kc = cg * 64 + (wn & 1) * 32 + nr * 16 + ln;
                out[((size_t)row * 256 + kc) * 2 + comp] = acc[mr][nr][reg];
            }
        }
    }
}

// Epilogue: scale to norm 16, rotate by conj(exp(i p1.A)), add exp(i p1.P). In place.
__global__ __launch_bounds__(256) void epi_kernel(const float* __restrict__ p1,
                                                  const float* __restrict__ A,
                                                  const float* __restrict__ P,
                                                  const float* __restrict__ normpart,
                                                  float* __restrict__ out) {
    const int i = blockIdx.x;
    const int k = threadIdx.x;
    const float x = p1[(size_t)i * 3 + 0], y = p1[(size_t)i * 3 + 1], z = p1[(size_t)i * 3 + 2];
    const float ns = normpart[i] + normpart[N1 + i] + normpart[2 * N1 + i] + normpart[3 * N1 + i];
    const float scale = 16.0f * rsqrtf(ns);
    float th1 = fmaf(x, A[k], fmaf(y, A[256 + k], z * A[512 + k]));
    float thp = fmaf(x, P[k], fmaf(y, P[256 + k], z * P[512 + k]));
    float s1, c1, sp, cp;
    sincosf(th1, &s1, &c1);
    sincosf(thp, &sp, &cp);
    float2 gv = *(float2*)(out + ((size_t)i * 256 + k) * 2);
    float gr = gv.x, gi = gv.y;
    float2 res;
    res.x = fmaf(gr, c1, gi * s1) * scale + cp;
    res.y = fmaf(gi, c1, -gr * s1) * scale + sp;
    *(float2*)(out + ((size_t)i * 256 + k) * 2) = res;
}

extern "C" void kernel_launch(void* const* d_in, const int* in_sizes, int n_in,
                              void* d_out, int out_size, void* d_ws, size_t ws_size,
                              hipStream_t stream) {
    const float* p1 = (const float*)d_in[0];
    const float* p2 = (const float*)d_in[1];
    const float* A  = (const float*)d_in[2];
    const float* P  = (const float*)d_in[3];
    unsigned short* Vf = (unsigned short*)d_ws;                       // 8192x512 bf16 = 8.39 MB
    float* normpart = (float*)((char*)d_ws + (size_t)8388608);        // 4 x 8192 f32
    float* out = (float*)d_out;

    feat_kernel<<<N2 / 8, 512, 0, stream>>>(p2, A, Vf);
    gemm_kernel<<<256, 512, 0, stream>>>(p1, p2, Vf, out, normpart);
    epi_kernel<<<N1, 256, 0, stream>>>(p1, A, P, normpart, out);
}

// Round 3
// 164.521 us; speedup vs baseline: 11.7383x; 1.5580x over previous
//
#include <hip/hip_runtime.h>
#include <math.h>

#define N1 8192
#define N2 8192
// 40.5 * log2(e) and 2x that: exp(-40.5*d2) = exp2(-B2L*d2)
#define B2L  58.42914916f
#define B2L2 116.85829832f

typedef short bf16x8 __attribute__((ext_vector_type(8)));
typedef float f32x4 __attribute__((ext_vector_type(4)));
typedef unsigned short ushort8 __attribute__((ext_vector_type(8)));

__device__ __forceinline__ unsigned short bf16bits(float f) {
    union { float f; unsigned u; } x; x.f = f;
    unsigned r = x.u + 0x7fff + ((x.u >> 16) & 1);   // RNE
    return (unsigned short)(r >> 16);
}

// Vf layout: [kblock = k/8][n = 0..511][e = k%8] bf16.
// n in 0..255 -> cos(p2_k . A_n); n in 256..511 -> sin(p2_k . A_n).
__global__ __launch_bounds__(512) void feat_kernel(const float* __restrict__ p2,
                                                   const float* __restrict__ A,
                                                   unsigned short* __restrict__ Vf) {
    __shared__ float p2s[24];
    const int t = threadIdx.x;
    const int j0 = blockIdx.x * 8;
    if (t < 24) p2s[t] = p2[(size_t)j0 * 3 + t];
    __syncthreads();
    const int k = t & 255, part = t >> 8;
    const float a0 = A[k], a1 = A[256 + k], a2 = A[512 + k];
    ushort8 v8;
    #pragma unroll
    for (int j = 0; j < 8; ++j) {
        float th = fmaf(p2s[j * 3], a0, fmaf(p2s[j * 3 + 1], a1, p2s[j * 3 + 2] * a2));
        float s, c;
        sincosf(th, &s, &c);
        v8[j] = bf16bits(part ? s : c);
    }
    *(ushort8*)(Vf + (size_t)blockIdx.x * 4096 + t * 8) = v8;
}

__device__ __forceinline__ void loadQ(const float* __restrict__ p2, int kbase, int kp,
                                      float& qx0, float& qy0, float& qz0, float& e20,
                                      float& qx1, float& qy1, float& qz1, float& e21) {
    const float* q = p2 + (size_t)(kbase + kp * 2) * 3;
    qx0 = q[0]; qy0 = q[1]; qz0 = q[2];
    qx1 = q[3]; qy1 = q[4]; qz1 = q[5];
    e20 = -B2L * fmaf(qx0, qx0, fmaf(qy0, qy0, qz0 * qz0));
    e21 = -B2L * fmaf(qx1, qx1, fmaf(qy1, qy1, qz1 * qz1));
}

__device__ __forceinline__ void buildJ(unsigned int* __restrict__ Jdst, int kp, int tm,
                                       const float px[4], const float py[4],
                                       const float pz[4], const float e1[4],
                                       float qx0, float qy0, float qz0, float e20,
                                       float qx1, float qy1, float qz1, float e21) {
    #pragma unroll
    for (int rr = 0; rr < 4; ++rr) {
        int m = tm + rr * 16;
        float s0 = fmaf(px[rr], qx0, fmaf(py[rr], qy0, pz[rr] * qz0));
        float s1 = fmaf(px[rr], qx1, fmaf(py[rr], qy1, pz[rr] * qz1));
        float j0 = exp2f(fmaf(s0, B2L2, e1[rr] + e20));
        float j1 = exp2f(fmaf(s1, B2L2, e1[rr] + e21));
        unsigned int pk = (unsigned int)bf16bits(j0) | ((unsigned int)bf16bits(j1) << 16);
        int byte = (m * 128 + kp * 4) ^ ((m & 7) << 4);
        Jdst[byte >> 2] = pk;
    }
}

__device__ __forceinline__ void loadB(bf16x8 b[2][2], const unsigned short* __restrict__ Bbase,
                                      int jc, int g) {
    #pragma unroll
    for (int kk = 0; kk < 2; ++kk)
        #pragma unroll
        for (int nr = 0; nr < 2; ++nr)
            b[kk][nr] = *(const bf16x8*)(Bbase + (size_t)((jc >> 3) + kk * 4 + g) * 4096 + nr * 128);
}

__device__ __forceinline__ void mfmaStep(f32x4 acc[4][2], const unsigned int* __restrict__ Jsrc,
                                         bf16x8 b[2][2], int ln, int g) {
    #pragma unroll
    for (int kk = 0; kk < 2; ++kk)
        #pragma unroll
        for (int mr = 0; mr < 4; ++mr) {
            int m = mr * 16 + ln;
            int byte = (m * 128 + kk * 64 + g * 16) ^ ((m & 7) << 4);
            bf16x8 af = *(const bf16x8*)((const char*)Jsrc + byte);
            acc[mr][0] = __builtin_amdgcn_mfma_f32_16x16x32_bf16(af, b[kk][0], acc[mr][0], 0, 0, 0);
            acc[mr][1] = __builtin_amdgcn_mfma_f32_16x16x32_bf16(af, b[kk][1], acc[mr][1], 0, 0, 0);
        }
}

// BM=64 rows x BN=256 cols (cg=0 -> re/cos cols, cg=1 -> im/sin cols). Grid 128x2=256.
// 8 waves, layout 1x8: every wave covers all 64 rows, 32 distinct cols -> B read once.
// Jlds ping-pong (JA/JB), B/q register-prefetched one 64-k step ahead, 1 barrier/step.
__global__ __launch_bounds__(512) void gemm_kernel(const float* __restrict__ p1,
                                                   const float* __restrict__ p2,
                                                   const unsigned short* __restrict__ Vf,
                                                   float* __restrict__ out,
                                                   float* __restrict__ normpart) {
    __shared__ unsigned int JA[2048];   // 64 rows x 64 k bf16, XOR-swizzled
    __shared__ unsigned int JB[2048];
    __shared__ float normp[8][64];

    const int t = threadIdx.x;
    const int l = t & 63;
    const int wn = t >> 6;        // 0..7 col group (32 cols)
    const int g = l >> 4;
    const int ln = l & 15;
    const int cg = blockIdx.x & 1;
    const int i0 = (int)(blockIdx.x >> 1) * 64;

    // J-build assignment: thread owns k-pair kp, rows tm+16*rr
    const int kp = t & 31;
    const int tm = t >> 5;        // 0..15
    float px[4], py[4], pz[4], e1[4];
    #pragma unroll
    for (int rr = 0; rr < 4; ++rr) {
        const float* pp = p1 + (size_t)(i0 + tm + rr * 16) * 3;
        px[rr] = pp[0]; py[rr] = pp[1]; pz[rr] = pp[2];
        e1[rr] = -B2L * fmaf(px[rr], px[rr], fmaf(py[rr], py[rr], pz[rr] * pz[rr]));
    }

    f32x4 acc[4][2] = {};
    const unsigned short* Bbase = Vf + (size_t)(cg * 256 + wn * 32 + ln) * 8;

    bf16x8 bA[2][2], bB[2][2];
    float qx0, qy0, qz0, e20, qx1, qy1, qz1, e21;   // q set "A-side"
    float rx0, ry0, rz0, f20, rx1, ry1, rz1, f21;   // q set "B-side"

    // prologue: J(0) -> JA, B(0) -> bA, q(64) -> r
    loadQ(p2, 0, kp, qx0, qy0, qz0, e20, qx1, qy1, qz1, e21);
    buildJ(JA, kp, tm, px, py, pz, e1, qx0, qy0, qz0, e20, qx1, qy1, qz1, e21);
    loadB(bA, Bbase, 0, g);
    loadQ(p2, 64, kp, rx0, ry0, rz0, f20, rx1, ry1, rz1, f21);

    for (int jc = 0; jc < N2; jc += 128) {
        // ---- step A: consume JA/bA (k=jc), build JB (k=jc+64), fetch bB/q ----
        __syncthreads();
        loadB(bB, Bbase, (jc + 64) & (N2 - 1), g);
        buildJ(JB, kp, tm, px, py, pz, e1, rx0, ry0, rz0, f20, rx1, ry1, rz1, f21);
        loadQ(p2, (jc + 128) & (N2 - 1), kp, qx0, qy0, qz0, e20, qx1, qy1, qz1, e21);
        mfmaStep(acc, JA, bA, ln, g);
        // ---- step B: consume JB/bB (k=jc+64), build JA (k=jc+128), fetch bA/q ----
        __syncthreads();
        loadB(bA, Bbase, (jc + 128) & (N2 - 1), g);
        buildJ(JA, kp, tm, px, py, pz, e1, qx0, qy0, qz0, e20, qx1, qy1, qz1, e21);
        loadQ(p2, (jc + 192) & (N2 - 1), kp, rx0, ry0, rz0, f20, rx1, ry1, rz1, f21);
        mfmaStep(acc, JB, bB, ln, g);
    }

    // ---- row-norm partials: sum of squares over this block's 256 cols ----
    #pragma unroll
    for (int mr = 0; mr < 4; ++mr) {
        #pragma unroll
        for (int reg = 0; reg < 4; ++reg) {
            float s = acc[mr][0][reg] * acc[mr][0][reg] + acc[mr][1][reg] * acc[mr][1][reg];
            #pragma unroll
            for (int off = 1; off < 16; off <<= 1) s += __shfl_xor(s, off, 64);
            if (ln == 0) normp[wn][mr * 16 + g * 4 + reg] = s;
        }
    }
    __syncthreads();
    if (t < 64) {
        float s = 0.f;
        #pragma unroll
        for (int w = 0; w < 8; ++w) s += normp[w][t];
        normpart[(size_t)cg * N1 + i0 + t] = s;
    }

    // ---- store raw G into out ----
    #pragma unroll
    for (int mr = 0; mr < 4; ++mr) {
        #pragma unroll
        for (int reg = 0; reg < 4; ++reg) {
            int row = i0 + mr * 16 + g * 4 + reg;
            #pragma unroll
            for (int nr = 0; nr < 2; ++nr) {
                int kc = wn * 32 + nr * 16 + ln;
                out[((size_t)row * 256 + kc) * 2 + cg] = acc[mr][nr][reg];
            }
        }
    }
}

// Epilogue: scale to norm 16, rotate by conj(exp(i p1.A)), add exp(i p1.P). In place.
__global__ __launch_bounds__(256) void epi_kernel(const float* __restrict__ p1,
                                                  const float* __restrict__ A,
                                                  const float* __restrict__ P,
                                                  const float* __restrict__ normpart,
                                                  float* __restrict__ out) {
    const int i = blockIdx.x;
    const int k = threadIdx.x;
    const float x = p1[(size_t)i * 3 + 0], y = p1[(size_t)i * 3 + 1], z = p1[(size_t)i * 3 + 2];
    const float ns = normpart[i] + normpart[N1 + i];
    const float scale = 16.0f * rsqrtf(ns);
    float th1 = fmaf(x, A[k], fmaf(y, A[256 + k], z * A[512 + k]));
    float thp = fmaf(x, P[k], fmaf(y, P[256 + k], z * P[512 + k]));
    float s1, c1, sp, cp;
    sincosf(th1, &s1, &c1);
    sincosf(thp, &sp, &cp);
    float2 gv = *(float2*)(out + ((size_t)i * 256 + k) * 2);
    float gr = gv.x, gi = gv.y;
    float2 res;
    res.x = fmaf(gr, c1, gi * s1) * scale + cp;
    res.y = fmaf(gi, c1, -gr * s1) * scale + sp;
    *(float2*)(out + ((size_t)i * 256 + k) * 2) = res;
}

extern "C" void kernel_launch(void* const* d_in, const int* in_sizes, int n_in,
                              void* d_out, int out_size, void* d_ws, size_t ws_size,
                              hipStream_t stream) {
    const float* p1 = (const float*)d_in[0];
    const float* p2 = (const float*)d_in[1];
    const float* A  = (const float*)d_in[2];
    const float* P  = (const float*)d_in[3];
    unsigned short* Vf = (unsigned short*)d_ws;                  // 8192x512 bf16 = 8.39 MB
    float* normpart = (float*)((char*)d_ws + (size_t)8388608);   // 2 x 8192 f32
    float* out = (float*)d_out;

    feat_kernel<<<N2 / 8, 512, 0, stream>>>(p2, A, Vf);
    gemm_kernel<<<256, 512, 0, stream>>>(p1, p2, Vf, out, normpart);
    epi_kernel<<<N1, 256, 0, stream>>>(p1, A, P, normpart, out);
}

// Round 5
// 145.294 us; speedup vs baseline: 13.2916x; 1.1323x over previous
//
#include <hip/hip_runtime.h>
#include <math.h>

#define N1 8192
#define N2 8192
// 40.5 * log2(e) and 2x that: exp(-40.5*d2) = exp2(-B2L*d2)
#define B2L  58.42914916f
#define B2L2 116.85829832f

typedef short bf16x8 __attribute__((ext_vector_type(8)));
typedef float f32x4 __attribute__((ext_vector_type(4)));
typedef unsigned short ushort8 __attribute__((ext_vector_type(8)));

__device__ __forceinline__ unsigned short bf16bits(float f) {
    union { float f; unsigned u; } x; x.f = f;
    unsigned r = x.u + 0x7fff + ((x.u >> 16) & 1);   // RNE
    return (unsigned short)(r >> 16);
}

// Vf layout: [kblock = k/8][n = 0..511][e = k%8] bf16.
// n in 0..255 -> cos(p2_k . A_n); n in 256..511 -> sin(p2_k . A_n).
__global__ __launch_bounds__(512) void feat_kernel(const float* __restrict__ p2,
                                                   const float* __restrict__ A,
                                                   unsigned short* __restrict__ Vf) {
    __shared__ float p2s[24];
    const int t = threadIdx.x;
    const int j0 = blockIdx.x * 8;
    if (t < 24) p2s[t] = p2[(size_t)j0 * 3 + t];
    __syncthreads();
    const int k = t & 255, part = t >> 8;
    const float a0 = A[k], a1 = A[256 + k], a2 = A[512 + k];
    ushort8 v8;
    #pragma unroll
    for (int j = 0; j < 8; ++j) {
        float th = fmaf(p2s[j * 3], a0, fmaf(p2s[j * 3 + 1], a1, p2s[j * 3 + 2] * a2));
        float s, c;
        sincosf(th, &s, &c);
        v8[j] = bf16bits(part ? s : c);
    }
    *(ushort8*)(Vf + (size_t)blockIdx.x * 4096 + t * 8) = v8;
}

__device__ __forceinline__ void loadQ(const float* __restrict__ p2, int kbase, int kp,
                                      float& qx0, float& qy0, float& qz0, float& e20,
                                      float& qx1, float& qy1, float& qz1, float& e21) {
    const float* q = p2 + (size_t)(kbase + kp * 2) * 3;
    qx0 = q[0]; qy0 = q[1]; qz0 = q[2];
    qx1 = q[3]; qy1 = q[4]; qz1 = q[5];
    e20 = -B2L * fmaf(qx0, qx0, fmaf(qy0, qy0, qz0 * qz0));
    e21 = -B2L * fmaf(qx1, qx1, fmaf(qy1, qy1, qz1 * qz1));
}

// J tile build: 32 rows x 64 k. Thread owns k-pair kp (2 cols) x rows tm, tm+16.
__device__ __forceinline__ void buildJ(unsigned int* __restrict__ Jdst, int kp, int tm,
                                       const float px[2], const float py[2],
                                       const float pz[2], const float e1[2],
                                       float qx0, float qy0, float qz0, float e20,
                                       float qx1, float qy1, float qz1, float e21) {
    #pragma unroll
    for (int rr = 0; rr < 2; ++rr) {
        int m = tm + rr * 16;
        float s0 = fmaf(px[rr], qx0, fmaf(py[rr], qy0, pz[rr] * qz0));
        float s1 = fmaf(px[rr], qx1, fmaf(py[rr], qy1, pz[rr] * qz1));
        float j0 = exp2f(fmaf(s0, B2L2, e1[rr] + e20));
        float j1 = exp2f(fmaf(s1, B2L2, e1[rr] + e21));
        unsigned int pk = (unsigned int)bf16bits(j0) | ((unsigned int)bf16bits(j1) << 16);
        int byte = (m * 128 + kp * 4) ^ ((m & 7) << 4);
        Jdst[byte >> 2] = pk;
    }
}

__device__ __forceinline__ void loadB(bf16x8 b[2][2], const unsigned short* __restrict__ Bbase,
                                      int jc, int g) {
    #pragma unroll
    for (int kk = 0; kk < 2; ++kk)
        #pragma unroll
        for (int nr = 0; nr < 2; ++nr)
            b[kk][nr] = *(const bf16x8*)(Bbase + (size_t)((jc >> 3) + kk * 4 + g) * 4096 + nr * 128);
}

__device__ __forceinline__ void mfmaStep(f32x4 acc[2][2], const unsigned int* __restrict__ Jsrc,
                                         bf16x8 b[2][2], int ln, int g) {
    #pragma unroll
    for (int kk = 0; kk < 2; ++kk)
        #pragma unroll
        for (int mr = 0; mr < 2; ++mr) {
            int m = mr * 16 + ln;
            int byte = (m * 128 + kk * 64 + g * 16) ^ ((m & 7) << 4);
            bf16x8 af = *(const bf16x8*)((const char*)Jsrc + byte);
            acc[mr][0] = __builtin_amdgcn_mfma_f32_16x16x32_bf16(af, b[kk][0], acc[mr][0], 0, 0, 0);
            acc[mr][1] = __builtin_amdgcn_mfma_f32_16x16x32_bf16(af, b[kk][1], acc[mr][1], 0, 0, 0);
        }
}

// BM=32 rows x BN=256 cols (cg=0 -> re/cos, cg=1 -> im/sin). Grid 256x2=512
// -> 2 blocks/CU so out-of-phase blocks hide each other's barrier drains.
// 8 waves, layout 1x8; Jlds ping-pong, B/q register-prefetched, 1 barrier/64-k step.
__global__ __launch_bounds__(512, 4) void gemm_kernel(const float* __restrict__ p1,
                                                      const float* __restrict__ p2,
                                                      const unsigned short* __restrict__ Vf,
                                                      float* __restrict__ out,
                                                      float* __restrict__ normpart) {
    __shared__ unsigned int JA[1024];   // 32 rows x 64 k bf16, XOR-swizzled
    __shared__ unsigned int JB[1024];
    __shared__ float normp[8][32];

    const int t = threadIdx.x;
    const int l = t & 63;
    const int wn = t >> 6;        // 0..7 col group (32 cols)
    const int g = l >> 4;
    const int ln = l & 15;
    const int cg = blockIdx.x & 1;
    const int i0 = (int)(blockIdx.x >> 1) * 32;

    // J-build assignment: thread owns k-pair kp, rows tm, tm+16
    const int kp = t & 31;
    const int tm = t >> 5;        // 0..15
    float px[2], py[2], pz[2], e1[2];
    #pragma unroll
    for (int rr = 0; rr < 2; ++rr) {
        const float* pp = p1 + (size_t)(i0 + tm + rr * 16) * 3;
        px[rr] = pp[0]; py[rr] = pp[1]; pz[rr] = pp[2];
        e1[rr] = -B2L * fmaf(px[rr], px[rr], fmaf(py[rr], py[rr], pz[rr] * pz[rr]));
    }

    f32x4 acc[2][2] = {};
    const unsigned short* Bbase = Vf + (size_t)(cg * 256 + wn * 32 + ln) * 8;

    bf16x8 bA[2][2], bB[2][2];
    float qx0, qy0, qz0, e20, qx1, qy1, qz1, e21;   // q set "A-side"
    float rx0, ry0, rz0, f20, rx1, ry1, rz1, f21;   // q set "B-side"

    // prologue: J(0) -> JA, B(0) -> bA, q(64) -> r
    loadQ(p2, 0, kp, qx0, qy0, qz0, e20, qx1, qy1, qz1, e21);
    buildJ(JA, kp, tm, px, py, pz, e1, qx0, qy0, qz0, e20, qx1, qy1, qz1, e21);
    loadB(bA, Bbase, 0, g);
    loadQ(p2, 64, kp, rx0, ry0, rz0, f20, rx1, ry1, rz1, f21);

    for (int jc = 0; jc < N2; jc += 128) {
        // ---- step A: consume JA/bA (k=jc), build JB (k=jc+64), fetch bB/q ----
        __syncthreads();
        loadB(bB, Bbase, (jc + 64) & (N2 - 1), g);
        buildJ(JB, kp, tm, px, py, pz, e1, rx0, ry0, rz0, f20, rx1, ry1, rz1, f21);
        loadQ(p2, (jc + 128) & (N2 - 1), kp, qx0, qy0, qz0, e20, qx1, qy1, qz1, e21);
        mfmaStep(acc, JA, bA, ln, g);
        // ---- step B: consume JB/bB (k=jc+64), build JA (k=jc+128), fetch bA/q ----
        __syncthreads();
        loadB(bA, Bbase, (jc + 128) & (N2 - 1), g);
        buildJ(JA, kp, tm, px, py, pz, e1, qx0, qy0, qz0, e20, qx1, qy1, qz1, e21);
        loadQ(p2, (jc + 192) & (N2 - 1), kp, rx0, ry0, rz0, f20, rx1, ry1, rz1, f21);
        mfmaStep(acc, JB, bB, ln, g);
    }

    // ---- row-norm partials: sum of squares over this block's 256 cols ----
    #pragma unroll
    for (int mr = 0; mr < 2; ++mr) {
        #pragma unroll
        for (int reg = 0; reg < 4; ++reg) {
            float s = acc[mr][0][reg] * acc[mr][0][reg] + acc[mr][1][reg] * acc[mr][1][reg];
            #pragma unroll
            for (int off = 1; off < 16; off <<= 1) s += __shfl_xor(s, off, 64);
            if (ln == 0) normp[wn][mr * 16 + g * 4 + reg] = s;
        }
    }
    __syncthreads();
    if (t < 32) {
        float s = 0.f;
        #pragma unroll
        for (int w = 0; w < 8; ++w) s += normp[w][t];
        normpart[(size_t)cg * N1 + i0 + t] = s;
    }

    // ---- store raw G into out ----
    #pragma unroll
    for (int mr = 0; mr < 2; ++mr) {
        #pragma unroll
        for (int reg = 0; reg < 4; ++reg) {
            int row = i0 + mr * 16 + g * 4 + reg;
            #pragma unroll
            for (int nr = 0; nr < 2; ++nr) {
                int kc = wn * 32 + nr * 16 + ln;
                out[((size_t)row * 256 + kc) * 2 + cg] = acc[mr][nr][reg];
            }
        }
    }
}

// Epilogue: scale to norm 16, rotate by conj(exp(i p1.A)), add exp(i p1.P). In place.
__global__ __launch_bounds__(256) void epi_kernel(const float* __restrict__ p1,
                                                  const float* __restrict__ A,
                                                  const float* __restrict__ P,
                                                  const float* __restrict__ normpart,
                                                  float* __restrict__ out) {
    const int i = blockIdx.x;
    const int k = threadIdx.x;
    const float x = p1[(size_t)i * 3 + 0], y = p1[(size_t)i * 3 + 1], z = p1[(size_t)i * 3 + 2];
    const float ns = normpart[i] + normpart[N1 + i];
    const float scale = 16.0f * rsqrtf(ns);
    float th1 = fmaf(x, A[k], fmaf(y, A[256 + k], z * A[512 + k]));
    float thp = fmaf(x, P[k], fmaf(y, P[256 + k], z * P[512 + k]));
    float s1, c1, sp, cp;
    sincosf(th1, &s1, &c1);
    sincosf(thp, &sp, &cp);
    float2 gv = *(float2*)(out + ((size_t)i * 256 + k) * 2);
    float gr = gv.x, gi = gv.y;
    float2 res;
    res.x = fmaf(gr, c1, gi * s1) * scale + cp;
    res.y = fmaf(gi, c1, -gr * s1) * scale + sp;
    *(float2*)(out + ((size_t)i * 256 + k) * 2) = res;
}

extern "C" void kernel_launch(void* const* d_in, const int* in_sizes, int n_in,
                              void* d_out, int out_size, void* d_ws, size_t ws_size,
                              hipStream_t stream) {
    const float* p1 = (const float*)d_in[0];
    const float* p2 = (const float*)d_in[1];
    const float* A  = (const float*)d_in[2];
    const float* P  = (const float*)d_in[3];
    unsigned short* Vf = (unsigned short*)d_ws;                  // 8192x512 bf16 = 8.39 MB
    float* normpart = (float*)((char*)d_ws + (size_t)8388608);   // 2 x 8192 f32
    float* out = (float*)d_out;

    feat_kernel<<<N2 / 8, 512, 0, stream>>>(p2, A, Vf);
    gemm_kernel<<<512, 512, 0, stream>>>(p1, p2, Vf, out, normpart);
    epi_kernel<<<N1, 256, 0, stream>>>(p1, A, P, normpart, out);
}

// Round 6
// 143.995 us; speedup vs baseline: 13.4116x; 1.0090x over previous
//
#include <hip/hip_runtime.h>
#include <math.h>

#define N1 8192
#define N2 8192
// 40.5 * log2(e) and 2x that: exp(-40.5*d2) = exp2(-B2L*d2)
#define B2L  58.42914916f
#define B2L2 116.85829832f

typedef short bf16x8 __attribute__((ext_vector_type(8)));
typedef float f32x4 __attribute__((ext_vector_type(4)));
typedef unsigned short ushort8 __attribute__((ext_vector_type(8)));

__device__ __forceinline__ unsigned short bf16bits(float f) {
    union { float f; unsigned u; } x; x.f = f;
    unsigned r = x.u + 0x7fff + ((x.u >> 16) & 1);   // RNE
    return (unsigned short)(r >> 16);
}

// one v_cvt_pk_bf16_f32: D[15:0]=bf16(a), D[31:16]=bf16(b)  (T12 recipe)
__device__ __forceinline__ unsigned int cvt_pk_bf16(float a, float b) {
    unsigned int r;
    asm("v_cvt_pk_bf16_f32 %0, %1, %2" : "=v"(r) : "v"(a), "v"(b));
    return r;
}

// Vf layout: [kblock = k/8][n = 0..511][e = k%8] bf16.
// n in 0..255 -> cos(p2_k . A_n); n in 256..511 -> sin(p2_k . A_n).
__global__ __launch_bounds__(512) void feat_kernel(const float* __restrict__ p2,
                                                   const float* __restrict__ A,
                                                   unsigned short* __restrict__ Vf) {
    __shared__ float p2s[24];
    const int t = threadIdx.x;
    const int j0 = blockIdx.x * 8;
    if (t < 24) p2s[t] = p2[(size_t)j0 * 3 + t];
    __syncthreads();
    const int k = t & 255, part = t >> 8;
    const float a0 = A[k], a1 = A[256 + k], a2 = A[512 + k];
    ushort8 v8;
    #pragma unroll
    for (int j = 0; j < 8; ++j) {
        float th = fmaf(p2s[j * 3], a0, fmaf(p2s[j * 3 + 1], a1, p2s[j * 3 + 2] * a2));
        float s, c;
        sincosf(th, &s, &c);
        v8[j] = bf16bits(part ? s : c);
    }
    *(ushort8*)(Vf + (size_t)blockIdx.x * 4096 + t * 8) = v8;
}

// qoff = kp*6 (thread-const); kbase*3 is uniform -> SALU base.
__device__ __forceinline__ void loadQ(const float* __restrict__ p2, int kbase, int qoff,
                                      float& qx0, float& qy0, float& qz0, float& e20,
                                      float& qx1, float& qy1, float& qz1, float& e21) {
    const float* q = p2 + (size_t)(unsigned)(kbase * 3) + qoff;
    qx0 = q[0]; qy0 = q[1]; qz0 = q[2];
    qx1 = q[3]; qy1 = q[4]; qz1 = q[5];
    e20 = -B2L * fmaf(qx0, qx0, fmaf(qy0, qy0, qz0 * qz0));
    e21 = -B2L * fmaf(qx1, qx1, fmaf(qy1, qy1, qz1 * qz1));
}

// J tile build: 32 rows x 64 k. Thread owns k-pair kp (2 cols) x rows tm, tm+16.
// wrOfs[rr] precomputed: (m*128 + kp*4) ^ ((m&7)<<4), m = tm + rr*16.
__device__ __forceinline__ void buildJ(unsigned int* __restrict__ Jdst, const int wrOfs[2],
                                       const float px[2], const float py[2],
                                       const float pz[2], const float e1[2],
                                       float qx0, float qy0, float qz0, float e20,
                                       float qx1, float qy1, float qz1, float e21) {
    #pragma unroll
    for (int rr = 0; rr < 2; ++rr) {
        float s0 = fmaf(px[rr], qx0, fmaf(py[rr], qy0, pz[rr] * qz0));
        float s1 = fmaf(px[rr], qx1, fmaf(py[rr], qy1, pz[rr] * qz1));
        float j0 = exp2f(fmaf(s0, B2L2, e1[rr] + e20));
        float j1 = exp2f(fmaf(s1, B2L2, e1[rr] + e21));
        *(unsigned int*)((char*)Jdst + wrOfs[rr]) = cvt_pk_bf16(j0, j1);
    }
}

// pB = Vf + (jc>>3)*4096 (uniform); bOfs[kk][nr] thread-const.
__device__ __forceinline__ void loadB(bf16x8 b[2][2], const unsigned short* __restrict__ pB,
                                      const int bOfs[2][2]) {
    #pragma unroll
    for (int kk = 0; kk < 2; ++kk)
        #pragma unroll
        for (int nr = 0; nr < 2; ++nr)
            b[kk][nr] = *(const bf16x8*)(pB + bOfs[kk][nr]);
}

// rdOfs[kk][mr] precomputed: (m*128 + kk*64 + g*16) ^ ((m&7)<<4), m = mr*16 + ln.
__device__ __forceinline__ void mfmaStep(f32x4 acc[2][2], const unsigned int* __restrict__ Jsrc,
                                         bf16x8 b[2][2], const int rdOfs[2][2]) {
    #pragma unroll
    for (int kk = 0; kk < 2; ++kk)
        #pragma unroll
        for (int mr = 0; mr < 2; ++mr) {
            bf16x8 af = *(const bf16x8*)((const char*)Jsrc + rdOfs[kk][mr]);
            acc[mr][0] = __builtin_amdgcn_mfma_f32_16x16x32_bf16(af, b[kk][0], acc[mr][0], 0, 0, 0);
            acc[mr][1] = __builtin_amdgcn_mfma_f32_16x16x32_bf16(af, b[kk][1], acc[mr][1], 0, 0, 0);
        }
}

// BM=32 rows x BN=256 cols (cg=0 -> re/cos, cg=1 -> im/sin). Grid 256x2=512
// -> 2 blocks/CU so out-of-phase blocks hide each other's barrier drains.
// 8 waves, layout 1x8; Jlds ping-pong, B/q register-prefetched, 1 barrier/64-k step.
__global__ __launch_bounds__(512, 4) void gemm_kernel(const float* __restrict__ p1,
                                                      const float* __restrict__ p2,
                                                      const unsigned short* __restrict__ Vf,
                                                      float* __restrict__ out,
                                                      float* __restrict__ normpart) {
    __shared__ unsigned int JA[1024];   // 32 rows x 64 k bf16, XOR-swizzled
    __shared__ unsigned int JB[1024];
    __shared__ float normp[8][32];

    const int t = threadIdx.x;
    const int l = t & 63;
    const int wn = t >> 6;        // 0..7 col group (32 cols)
    const int g = l >> 4;
    const int ln = l & 15;
    const int cg = blockIdx.x & 1;
    const int i0 = (int)(blockIdx.x >> 1) * 32;

    // J-build assignment: thread owns k-pair kp, rows tm, tm+16
    const int kp = t & 31;
    const int tm = t >> 5;        // 0..15
    const int qoff = kp * 6;
    float px[2], py[2], pz[2], e1[2];
    int wrOfs[2];
    #pragma unroll
    for (int rr = 0; rr < 2; ++rr) {
        const float* pp = p1 + (size_t)(i0 + tm + rr * 16) * 3;
        px[rr] = pp[0]; py[rr] = pp[1]; pz[rr] = pp[2];
        e1[rr] = -B2L * fmaf(px[rr], px[rr], fmaf(py[rr], py[rr], pz[rr] * pz[rr]));
        int m = tm + rr * 16;
        wrOfs[rr] = (m * 128 + kp * 4) ^ ((m & 7) << 4);
    }

    int rdOfs[2][2];
    #pragma unroll
    for (int kk = 0; kk < 2; ++kk)
        #pragma unroll
        for (int mr = 0; mr < 2; ++mr) {
            int m = mr * 16 + ln;
            rdOfs[kk][mr] = (m * 128 + kk * 64 + g * 16) ^ ((m & 7) << 4);
        }

    int bOfs[2][2];
    #pragma unroll
    for (int kk = 0; kk < 2; ++kk)
        #pragma unroll
        for (int nr = 0; nr < 2; ++nr)
            bOfs[kk][nr] = (kk * 4 + g) * 4096 + (cg * 256 + wn * 32 + nr * 16 + ln) * 8;

    f32x4 acc[2][2] = {};

    bf16x8 bA[2][2], bB[2][2];
    float qx0, qy0, qz0, e20, qx1, qy1, qz1, e21;   // q set "A-side"
    float rx0, ry0, rz0, f20, rx1, ry1, rz1, f21;   // q set "B-side"

    // prologue: J(0) -> JA, B(0) -> bA, q(64) -> r
    loadQ(p2, 0, qoff, qx0, qy0, qz0, e20, qx1, qy1, qz1, e21);
    buildJ(JA, wrOfs, px, py, pz, e1, qx0, qy0, qz0, e20, qx1, qy1, qz1, e21);
    loadB(bA, Vf, bOfs);
    loadQ(p2, 64, qoff, rx0, ry0, rz0, f20, rx1, ry1, rz1, f21);

    for (int jc = 0; jc < N2; jc += 128) {
        // ---- step A: consume JA/bA (k=jc), build JB (k=jc+64), fetch bB/q ----
        __syncthreads();
        loadB(bB, Vf + ((unsigned)((jc + 64) & (N2 - 1)) >> 3) * 4096u, bOfs);
        buildJ(JB, wrOfs, px, py, pz, e1, rx0, ry0, rz0, f20, rx1, ry1, rz1, f21);
        loadQ(p2, (jc + 128) & (N2 - 1), qoff, qx0, qy0, qz0, e20, qx1, qy1, qz1, e21);
        mfmaStep(acc, JA, bA, rdOfs);
        // ---- step B: consume JB/bB (k=jc+64), build JA (k=jc+128), fetch bA/q ----
        __syncthreads();
        loadB(bA, Vf + ((unsigned)((jc + 128) & (N2 - 1)) >> 3) * 4096u, bOfs);
        buildJ(JA, wrOfs, px, py, pz, e1, qx0, qy0, qz0, e20, qx1, qy1, qz1, e21);
        loadQ(p2, (jc + 192) & (N2 - 1), qoff, rx0, ry0, rz0, f20, rx1, ry1, rz1, f21);
        mfmaStep(acc, JB, bB, rdOfs);
    }

    // ---- row-norm partials: sum of squares over this block's 256 cols ----
    #pragma unroll
    for (int mr = 0; mr < 2; ++mr) {
        #pragma unroll
        for (int reg = 0; reg < 4; ++reg) {
            float s = acc[mr][0][reg] * acc[mr][0][reg] + acc[mr][1][reg] * acc[mr][1][reg];
            #pragma unroll
            for (int off = 1; off < 16; off <<= 1) s += __shfl_xor(s, off, 64);
            if (ln == 0) normp[wn][mr * 16 + g * 4 + reg] = s;
        }
    }
    __syncthreads();
    if (t < 32) {
        float s = 0.f;
        #pragma unroll
        for (int w = 0; w < 8; ++w) s += normp[w][t];
        normpart[(size_t)cg * N1 + i0 + t] = s;
    }

    // ---- store raw G into out ----
    #pragma unroll
    for (int mr = 0; mr < 2; ++mr) {
        #pragma unroll
        for (int reg = 0; reg < 4; ++reg) {
            int row = i0 + mr * 16 + g * 4 + reg;
            #pragma unroll
            for (int nr = 0; nr < 2; ++nr) {
                int kc = wn * 32 + nr * 16 + ln;
                out[((size_t)row * 256 + kc) * 2 + cg] = acc[mr][nr][reg];
            }
        }
    }
}

// Epilogue: scale to norm 16, rotate by conj(exp(i p1.A)), add exp(i p1.P). In place.
__global__ __launch_bounds__(256) void epi_kernel(const float* __restrict__ p1,
                                                  const float* __restrict__ A,
                                                  const float* __restrict__ P,
                                                  const float* __restrict__ normpart,
                                                  float* __restrict__ out) {
    const int i = blockIdx.x;
    const int k = threadIdx.x;
    const float x = p1[(size_t)i * 3 + 0], y = p1[(size_t)i * 3 + 1], z = p1[(size_t)i * 3 + 2];
    const float ns = normpart[i] + normpart[N1 + i];
    const float scale = 16.0f * rsqrtf(ns);
    float th1 = fmaf(x, A[k], fmaf(y, A[256 + k], z * A[512 + k]));
    float thp = fmaf(x, P[k], fmaf(y, P[256 + k], z * P[512 + k]));
    float s1, c1, sp, cp;
    sincosf(th1, &s1, &c1);
    sincosf(thp, &sp, &cp);
    float2 gv = *(float2*)(out + ((size_t)i * 256 + k) * 2);
    float gr = gv.x, gi = gv.y;
    float2 res;
    res.x = fmaf(gr, c1, gi * s1) * scale + cp;
    res.y = fmaf(gi, c1, -gr * s1) * scale + sp;
    *(float2*)(out + ((size_t)i * 256 + k) * 2) = res;
}

extern "C" void kernel_launch(void* const* d_in, const int* in_sizes, int n_in,
                              void* d_out, int out_size, void* d_ws, size_t ws_size,
                              hipStream_t stream) {
    const float* p1 = (const float*)d_in[0];
    const float* p2 = (const float*)d_in[1];
    const float* A  = (const float*)d_in[2];
    const float* P  = (const float*)d_in[3];
    unsigned short* Vf = (unsigned short*)d_ws;                  // 8192x512 bf16 = 8.39 MB
    float* normpart = (float*)((char*)d_ws + (size_t)8388608);   // 2 x 8192 f32
    float* out = (float*)d_out;

    feat_kernel<<<N2 / 8, 512, 0, stream>>>(p2, A, Vf);
    gemm_kernel<<<512, 512, 0, stream>>>(p1, p2, Vf, out, normpart);
    epi_kernel<<<N1, 256, 0, stream>>>(p1, A, P, normpart, out);
}